// Round 1
// 935.673 us; speedup vs baseline: 1.0934x; 1.0934x over previous
//
#include <hip/hip_runtime.h>
#include <cstdint>
#include <cstddef>

#define Bq 256
#define Tq 1024
#define Sq 7
#define Hq 64
#define Lq 4
#define OUTq 3
#define Uq 8                     // timesteps per barrier beat
#define NTB (Tq / Uq)            // 128 work-beats per wave
#define NBEATS (NTB + Lq - 1)    // 131 total beats (pipeline fill)

typedef float vf16 __attribute__((ext_vector_type(16)));
typedef float vf4 __attribute__((ext_vector_type(4)));

// Systolic SNN scan, U=8 timesteps per beat. One block per batch element,
// 4 waves = 4 layers. Skew between adjacent layers is one beat = 8
// timesteps: wave l at beat k processes t = 8(k-l)..8(k-l)+7, consuming
// the 8 spike masks wave l-1 produced during beat k-1 (double-buffered in
// LDS). This amortizes the per-beat sync chain (ds_write -> lgkmcnt(0) ->
// s_barrier -> ds_read -> readfirstlane, ~1.1k cycles) over 8 timesteps:
// 1027 barriers -> 131.
// Numerics: per-element op order identical to the passing R1/R2 kernels
// (4-accumulator j-mod-4 fma chains, (a0+a1)+(a2+a3) combine, explicit
// __f*_rn LIF update) -> bit-identical results, only barrier cadence moved.
__global__ __launch_bounds__(256, 1) void snn_seq_kernel(
    const float* __restrict__ x,       // (B,T,S)
    const float* __restrict__ hs_in,   // (B,T,L,H)
    const float* __restrict__ w1,      // (H,S)
    const float* __restrict__ b1,      // (H)
    const float* __restrict__ w_h,     // (L-1,H,H)
    const float* __restrict__ b_h,     // (L-1,H)
    float* __restrict__ out_mem)       // (B,T,L,H)
{
    __shared__ __align__(16) unsigned long long lmask[2][Lq][Uq]; // [slot][producer layer][i]

    const int b = blockIdx.x;
    const int lane = threadIdx.x & 63;
    const int wv = threadIdx.x >> 6;   // 0..3 = layer index

    // membrane state for this wave's layer, init from hidden_states[:,0]
    float m = hs_in[(((size_t)b * Tq) * Lq + wv) * Hq + lane];
    float* omem = out_mem + ((size_t)b * Tq * Lq + wv) * Hq + lane;

    // wave-0 (input projection) state
    float w1r[Sq];
    float b1r = 0.0f;
    const float* xrow = x + (size_t)b * Tq * Sq;
    vf4 xcur[14];                      // current beat's 8 x-rows (56 floats)
    // waves 1..3 (recurrent) state: 64 weight floats in registers
    vf16 W0, W1, W2, W3;
    float bhr = 0.0f;

    if (wv == 0) {
#pragma unroll
        for (int s = 0; s < Sq; ++s) w1r[s] = w1[lane * Sq + s];
        b1r = b1[lane];
        const vf4* xp4 = (const vf4*)xrow;   // beat 0 rows (uniform broadcast loads)
#pragma unroll
        for (int i = 0; i < 14; ++i) xcur[i] = xp4[i];
    } else {
        const vf16* wr = (const vf16*)(w_h + ((size_t)((wv - 1) * Hq + lane)) * Hq);
        W0 = wr[0]; W1 = wr[1]; W2 = wr[2]; W3 = wr[3];
        bhr = b_h[(wv - 1) * Hq + lane];
    }

#define XC(e) xcur[(e) >> 2][(e) & 3]

#define DOBLK(Wv, word, base)                                        \
    {                                                                \
        _Pragma("unroll") for (int q = 0; q < 4; ++q)                \
        {                                                            \
            float f0 = ((word >> (base + 4 * q + 0)) & 1u) ? 1.0f : 0.0f; \
            float f1 = ((word >> (base + 4 * q + 1)) & 1u) ? 1.0f : 0.0f; \
            float f2 = ((word >> (base + 4 * q + 2)) & 1u) ? 1.0f : 0.0f; \
            float f3 = ((word >> (base + 4 * q + 3)) & 1u) ? 1.0f : 0.0f; \
            a0 = fmaf(f0, Wv[4 * q + 0], a0);                        \
            a1 = fmaf(f1, Wv[4 * q + 1], a1);                        \
            a2 = fmaf(f2, Wv[4 * q + 2], a2);                        \
            a3 = fmaf(f3, Wv[4 * q + 3], a3);                        \
        }                                                            \
    }

    for (int k = 0; k < NBEATS; ++k) {
        if (wv == 0) {
            if (k < NTB) {
                // prefetch next beat's 8 x-rows (latency spans this beat's compute)
                const int kp = (k < NTB - 1) ? k + 1 : k;
                const vf4* xp4 = (const vf4*)(xrow + (size_t)kp * (Uq * Sq));
                vf4 xn[14];
#pragma unroll
                for (int i = 0; i < 14; ++i) xn[i] = xp4[i];

#pragma unroll
                for (int i = 0; i < Uq; ++i) {
                    float cur = b1r;
#pragma unroll
                    for (int s = 0; s < Sq; ++s) cur = fmaf(XC(i * Sq + s), w1r[s], cur);
                    float rst = (m > 1.0f) ? 1.0f : 0.0f;
                    float mn = __fadd_rn(__fmul_rn(0.8f, m), cur);
                    mn = __fsub_rn(mn, rst);
                    m = mn;
                    omem[(size_t)(k * Uq + i) * (Lq * Hq)] = mn;  // fire-and-forget
                    unsigned long long msk = __ballot(mn > 1.0f);
                    if (lane == 0) lmask[k & 1][0][i] = msk;
                }
#pragma unroll
                for (int i = 0; i < 14; ++i) xcur[i] = xn[i];
            }
        } else {
            const int tt = k - wv;
            if (tt >= 0 && tt < NTB) {
                // 8 spike masks from previous layer, produced last beat
                const uint4* mp = (const uint4*)&lmask[(k - 1) & 1][wv - 1][0];
                uint4 q0 = mp[0], q1 = mp[1], q2 = mp[2], q3 = mp[3];
                unsigned mw[16] = {q0.x, q0.y, q0.z, q0.w,
                                   q1.x, q1.y, q1.z, q1.w,
                                   q2.x, q2.y, q2.z, q2.w,
                                   q3.x, q3.y, q3.z, q3.w};
#pragma unroll
                for (int i = 0; i < Uq; ++i) {
                    unsigned lo = (unsigned)__builtin_amdgcn_readfirstlane((int)mw[2 * i + 0]);
                    unsigned hi = (unsigned)__builtin_amdgcn_readfirstlane((int)mw[2 * i + 1]);

                    float a0 = bhr, a1 = 0.0f, a2 = 0.0f, a3 = 0.0f;
                    DOBLK(W0, lo, 0)
                    DOBLK(W1, lo, 16)
                    DOBLK(W2, hi, 0)
                    DOBLK(W3, hi, 16)
                    float cur = __fadd_rn(__fadd_rn(a0, a1), __fadd_rn(a2, a3));

                    float rst = (m > 1.0f) ? 1.0f : 0.0f;
                    float mn = __fadd_rn(__fmul_rn(0.8f, m), cur);
                    mn = __fsub_rn(mn, rst);
                    m = mn;
                    omem[(size_t)(tt * Uq + i) * (Lq * Hq)] = mn;

                    if (wv < Lq - 1) {
                        unsigned long long msk = __ballot(mn > 1.0f);
                        if (lane == 0) lmask[k & 1][wv][i] = msk;
                    }
                }
            }
        }
        // beat barrier: drain LDS (mask handoff) but NOT vmem stores
        asm volatile("s_waitcnt lgkmcnt(0)\n\ts_barrier" ::: "memory");
    }
#undef DOBLK
#undef XC
}

// Readout deferred out of the sequential path: recompute layer-3 spikes from
// the stored membrane states. 16 lanes per (b,t) row.
__global__ __launch_bounds__(256) void snn_out_kernel(
    const float* __restrict__ mem,    // (B,T,L,H)
    const float* __restrict__ w_out,  // (OUT,H)
    const float* __restrict__ b_out,  // (OUT)
    float* __restrict__ out0)         // (B,T,OUT)
{
    const long long idx = (long long)blockIdx.x * 16 + (threadIdx.x >> 4); // b*T + t
    const int sub = threadIdx.x & 15;
    if (idx >= (long long)Bq * Tq) return;

    float4 mv = ((const float4*)mem)[(size_t)idx * 64 + 48 + sub];
    float4 s;
    s.x = (mv.x > 1.0f) ? 1.0f : 0.0f;
    s.y = (mv.y > 1.0f) ? 1.0f : 0.0f;
    s.z = (mv.z > 1.0f) ? 1.0f : 0.0f;
    s.w = (mv.w > 1.0f) ? 1.0f : 0.0f;

#pragma unroll
    for (int o = 0; o < OUTq; ++o) {
        float4 wv = ((const float4*)w_out)[o * 16 + sub];
        float v = s.x * wv.x + s.y * wv.y + s.z * wv.z + s.w * wv.w;
#pragma unroll
        for (int off = 8; off > 0; off >>= 1) v += __shfl_xor(v, off, 16);
        if (sub == 0) out0[idx * OUTq + o] = v + b_out[o];
    }
}

__global__ __launch_bounds__(256) void copy_x_kernel(
    const float4* __restrict__ src, float4* __restrict__ dst, int n4)
{
    int i = blockIdx.x * 256 + threadIdx.x;
    if (i < n4) dst[i] = src[i];
}

extern "C" void kernel_launch(void* const* d_in, const int* in_sizes, int n_in,
                              void* d_out, int out_size, void* d_ws, size_t ws_size,
                              hipStream_t stream) {
    const float* x     = (const float*)d_in[0];
    const float* hs_in = (const float*)d_in[1];
    // d_in[2] = prev_obs (unused by reference)
    const float* w1    = (const float*)d_in[3];
    const float* b1    = (const float*)d_in[4];
    const float* w_h   = (const float*)d_in[5];
    const float* b_h   = (const float*)d_in[6];
    const float* w_out = (const float*)d_in[7];
    const float* b_out = (const float*)d_in[8];

    float* out0 = (float*)d_out;                                   // (B,T,OUT)
    float* out1 = out0 + (size_t)Bq * Tq * OUTq;                   // (B,T,L,H)
    float* out2 = out1 + (size_t)Bq * Tq * Lq * Hq;                // (B,T,S) = x

    // 1) systolic sequential SNN scan: writes new_hidden_states
    snn_seq_kernel<<<Bq, 256, 0, stream>>>(x, hs_in, w1, b1, w_h, b_h, out1);

    // 2) readout from stored layer-3 membranes
    const long long nbt = (long long)Bq * Tq;
    snn_out_kernel<<<(int)(nbt / 16), 256, 0, stream>>>(out1, w_out, b_out, out0);

    // 3) passthrough copy of x
    const int n4 = Bq * Tq * Sq / 4;
    copy_x_kernel<<<(n4 + 255) / 256, 256, 0, stream>>>((const float4*)x, (float4*)out2, n4);
}

// Round 7
// 904.445 us; speedup vs baseline: 1.1311x; 1.0345x over previous
//
#include <hip/hip_runtime.h>
#include <cstdint>
#include <cstddef>

#define Bq 256
#define Tq 1024
#define Sq 7
#define Hq 64
#define Lq 4
#define OUTq 3
#define Uq 8                     // timesteps per barrier beat
#define NTB (Tq / Uq)            // 128 work-beats per wave
#define NBEATS (NTB + Lq - 1)    // 131 total beats (pipeline fill)

typedef float vf16 __attribute__((ext_vector_type(16)));
typedef float vf4 __attribute__((ext_vector_type(4)));

// Scalar-side bit test: the spike mask word is wave-uniform (SGPR after
// readfirstlane). s_bitcmp1 + s_cselect produce f in {0.0f,1.0f} on the
// SALU pipe (1 cyc each, scc confined to this asm block), leaving exactly
// ONE VALU op per weight element (v_fmac with SGPR src0). The compiler's
// default lowering used ~4 dependent VALU ops/element (v1 measured ~267
// VALU inst/timestep for the 64-elem dot product -> 60% dep-latency
// bubbles at 84 VGPRs). Producer/consumer are separate non-volatile asm
// blocks so the scheduler can hoist bit tests ahead of the fmac chain.
template<int BIT>
__device__ __forceinline__ float selbit(unsigned ws) {
    float f;
    asm("s_bitcmp1_b32 %1, %2\n\ts_cselect_b32 %0, 1.0, 0"
        : "=s"(f) : "s"(ws), "i"(BIT) : "scc");
    return f;
}

__device__ __forceinline__ void sfmac(float& a, float f, float w) {
    asm("v_fmac_f32 %0, %1, %2" : "+v"(a) : "s"(f), "v"(w));
}

// Systolic SNN scan, U=8 timesteps per beat. One block per batch element,
// 4 waves = 4 layers. Skew between adjacent layers is one beat = 8
// timesteps: wave l at beat k processes t = 8(k-l)..8(k-l)+7, consuming
// the 8 spike masks wave l-1 produced during beat k-1 (double-buffered in
// LDS). 131 barriers total.
// Numerics: per-element op order identical to the passing kernels
// (4-accumulator j-mod-4 chains, (a0+a1)+(a2+a3) combine, explicit
// __f*_rn LIF update); f in {0,1} exact -> bit-identical results.
__global__ __launch_bounds__(256, 1) void snn_seq_kernel(
    const float* __restrict__ x,       // (B,T,S)
    const float* __restrict__ hs_in,   // (B,T,L,H)
    const float* __restrict__ w1,      // (H,S)
    const float* __restrict__ b1,      // (H)
    const float* __restrict__ w_h,     // (L-1,H,H)
    const float* __restrict__ b_h,     // (L-1,H)
    float* __restrict__ out_mem)       // (B,T,L,H)
{
    __shared__ __align__(16) unsigned long long lmask[2][Lq][Uq]; // [slot][producer layer][i]

    const int b = blockIdx.x;
    const int lane = threadIdx.x & 63;
    const int wv = threadIdx.x >> 6;   // 0..3 = layer index

    // membrane state for this wave's layer, init from hidden_states[:,0]
    float m = hs_in[(((size_t)b * Tq) * Lq + wv) * Hq + lane];
    float* omem = out_mem + ((size_t)b * Tq * Lq + wv) * Hq + lane;

    // wave-0 (input projection) state
    float w1r[Sq];
    float b1r = 0.0f;
    const float* xrow = x + (size_t)b * Tq * Sq;
    vf4 xcur[14];                      // current beat's 8 x-rows (56 floats)
    // waves 1..3 (recurrent) state: 64 weight floats in registers
    vf16 W0, W1, W2, W3;
    float bhr = 0.0f;

    if (wv == 0) {
#pragma unroll
        for (int s = 0; s < Sq; ++s) w1r[s] = w1[lane * Sq + s];
        b1r = b1[lane];
        const vf4* xp4 = (const vf4*)xrow;   // beat 0 rows (uniform broadcast loads)
#pragma unroll
        for (int i = 0; i < 14; ++i) xcur[i] = xp4[i];
    } else {
        const vf16* wr = (const vf16*)(w_h + ((size_t)((wv - 1) * Hq + lane)) * Hq);
        W0 = wr[0]; W1 = wr[1]; W2 = wr[2]; W3 = wr[3];
        bhr = b_h[(wv - 1) * Hq + lane];
    }

#define XC(e) xcur[(e) >> 2][(e) & 3]

    // 4 elements (one q-group) of one 16-wide block; BASE/QQ are literals so
    // the selbit<> template arg is a compile-time constant.
#define DOQ(Wv, ws, BASE, QQ)                                        \
    {                                                                \
        float f0 = selbit<(BASE) + 4 * (QQ) + 0>(ws);                \
        float f1 = selbit<(BASE) + 4 * (QQ) + 1>(ws);                \
        float f2 = selbit<(BASE) + 4 * (QQ) + 2>(ws);                \
        float f3 = selbit<(BASE) + 4 * (QQ) + 3>(ws);                \
        sfmac(a0, f0, Wv[4 * (QQ) + 0]);                             \
        sfmac(a1, f1, Wv[4 * (QQ) + 1]);                             \
        sfmac(a2, f2, Wv[4 * (QQ) + 2]);                             \
        sfmac(a3, f3, Wv[4 * (QQ) + 3]);                             \
    }
#define DOBLK(Wv, ws, BASE)                                          \
    DOQ(Wv, ws, BASE, 0) DOQ(Wv, ws, BASE, 1)                        \
    DOQ(Wv, ws, BASE, 2) DOQ(Wv, ws, BASE, 3)

    for (int k = 0; k < NBEATS; ++k) {
        if (wv == 0) {
            if (k < NTB) {
                // prefetch next beat's 8 x-rows (latency spans this beat's compute)
                const int kp = (k < NTB - 1) ? k + 1 : k;
                const vf4* xp4 = (const vf4*)(xrow + (size_t)kp * (Uq * Sq));
                vf4 xn[14];
#pragma unroll
                for (int i = 0; i < 14; ++i) xn[i] = xp4[i];

                unsigned long long produced[Uq];
#pragma unroll
                for (int i = 0; i < Uq; ++i) {
                    float cur = b1r;
#pragma unroll
                    for (int s = 0; s < Sq; ++s) cur = fmaf(XC(i * Sq + s), w1r[s], cur);
                    float rst = (m > 1.0f) ? 1.0f : 0.0f;
                    float mn = __fadd_rn(__fmul_rn(0.8f, m), cur);
                    mn = __fsub_rn(mn, rst);
                    m = mn;
                    omem[(size_t)(k * Uq + i) * (Lq * Hq)] = mn;  // fire-and-forget
                    produced[i] = __ballot(mn > 1.0f);
                }
                if (lane == 0) {
#pragma unroll
                    for (int i = 0; i < Uq; ++i) lmask[k & 1][0][i] = produced[i];
                }
#pragma unroll
                for (int i = 0; i < 14; ++i) xcur[i] = xn[i];
            }
        } else {
            const int tt = k - wv;
            if (tt >= 0 && tt < NTB) {
                // 8 spike masks from previous layer, produced last beat
                const uint4* mp = (const uint4*)&lmask[(k - 1) & 1][wv - 1][0];
                uint4 q0 = mp[0], q1 = mp[1], q2 = mp[2], q3 = mp[3];
                unsigned mw[16] = {q0.x, q0.y, q0.z, q0.w,
                                   q1.x, q1.y, q1.z, q1.w,
                                   q2.x, q2.y, q2.z, q2.w,
                                   q3.x, q3.y, q3.z, q3.w};
                unsigned long long produced[Uq];
#pragma unroll
                for (int i = 0; i < Uq; ++i) {
                    unsigned lo = (unsigned)__builtin_amdgcn_readfirstlane((int)mw[2 * i + 0]);
                    unsigned hi = (unsigned)__builtin_amdgcn_readfirstlane((int)mw[2 * i + 1]);

                    float a0 = bhr, a1 = 0.0f, a2 = 0.0f, a3 = 0.0f;
                    DOBLK(W0, lo, 0)
                    DOBLK(W1, lo, 16)
                    DOBLK(W2, hi, 0)
                    DOBLK(W3, hi, 16)
                    float cur = __fadd_rn(__fadd_rn(a0, a1), __fadd_rn(a2, a3));

                    float rst = (m > 1.0f) ? 1.0f : 0.0f;
                    float mn = __fadd_rn(__fmul_rn(0.8f, m), cur);
                    mn = __fsub_rn(mn, rst);
                    m = mn;
                    omem[(size_t)(tt * Uq + i) * (Lq * Hq)] = mn;
                    produced[i] = __ballot(mn > 1.0f);
                }
                if (wv < Lq - 1 && lane == 0) {
#pragma unroll
                    for (int i = 0; i < Uq; ++i) lmask[k & 1][wv][i] = produced[i];
                }
            }
        }
        // beat barrier: drain LDS (mask handoff) but NOT vmem stores
        asm volatile("s_waitcnt lgkmcnt(0)\n\ts_barrier" ::: "memory");
    }
#undef DOBLK
#undef DOQ
#undef XC
}

// Readout deferred out of the sequential path: recompute layer-3 spikes from
// the stored membrane states. 16 lanes per (b,t) row.
__global__ __launch_bounds__(256) void snn_out_kernel(
    const float* __restrict__ mem,    // (B,T,L,H)
    const float* __restrict__ w_out,  // (OUT,H)
    const float* __restrict__ b_out,  // (OUT)
    float* __restrict__ out0)         // (B,T,OUT)
{
    const long long idx = (long long)blockIdx.x * 16 + (threadIdx.x >> 4); // b*T + t
    const int sub = threadIdx.x & 15;
    if (idx >= (long long)Bq * Tq) return;

    float4 mv = ((const float4*)mem)[(size_t)idx * 64 + 48 + sub];
    float4 s;
    s.x = (mv.x > 1.0f) ? 1.0f : 0.0f;
    s.y = (mv.y > 1.0f) ? 1.0f : 0.0f;
    s.z = (mv.z > 1.0f) ? 1.0f : 0.0f;
    s.w = (mv.w > 1.0f) ? 1.0f : 0.0f;

#pragma unroll
    for (int o = 0; o < OUTq; ++o) {
        float4 wv = ((const float4*)w_out)[o * 16 + sub];
        float v = s.x * wv.x + s.y * wv.y + s.z * wv.z + s.w * wv.w;
#pragma unroll
        for (int off = 8; off > 0; off >>= 1) v += __shfl_xor(v, off, 16);
        if (sub == 0) out0[idx * OUTq + o] = v + b_out[o];
    }
}

__global__ __launch_bounds__(256) void copy_x_kernel(
    const float4* __restrict__ src, float4* __restrict__ dst, int n4)
{
    int i = blockIdx.x * 256 + threadIdx.x;
    if (i < n4) dst[i] = src[i];
}

extern "C" void kernel_launch(void* const* d_in, const int* in_sizes, int n_in,
                              void* d_out, int out_size, void* d_ws, size_t ws_size,
                              hipStream_t stream) {
    const float* x     = (const float*)d_in[0];
    const float* hs_in = (const float*)d_in[1];
    // d_in[2] = prev_obs (unused by reference)
    const float* w1    = (const float*)d_in[3];
    const float* b1    = (const float*)d_in[4];
    const float* w_h   = (const float*)d_in[5];
    const float* b_h   = (const float*)d_in[6];
    const float* w_out = (const float*)d_in[7];
    const float* b_out = (const float*)d_in[8];

    float* out0 = (float*)d_out;                                   // (B,T,OUT)
    float* out1 = out0 + (size_t)Bq * Tq * OUTq;                   // (B,T,L,H)
    float* out2 = out1 + (size_t)Bq * Tq * Lq * Hq;                // (B,T,S) = x

    // 1) systolic sequential SNN scan: writes new_hidden_states
    snn_seq_kernel<<<Bq, 256, 0, stream>>>(x, hs_in, w1, b1, w_h, b_h, out1);

    // 2) readout from stored layer-3 membranes
    const long long nbt = (long long)Bq * Tq;
    snn_out_kernel<<<(int)(nbt / 16), 256, 0, stream>>>(out1, w_out, b_out, out0);

    // 3) passthrough copy of x
    const int n4 = Bq * Tq * Sq / 4;
    copy_x_kernel<<<(n4 + 255) / 256, 256, 0, stream>>>((const float4*)x, (float4*)out2, n4);
}